// Round 2
// baseline (914.474 us; speedup 1.0000x reference)
//
#include <hip/hip_runtime.h>

#define Bk 16
#define Hk 256
#define Lk 8192
#define N2k 32
#define Sk 256
#define Gk (Lk / Sk) // 32
#define HALF_MODES 16

// Workspace layout (bytes):
//   W  (float2[H*N2])  @ 0        : w = exp(dt*A)
//   CT (float2[H*N2])  @ 65536    : 2*C*(w-1)/A   (only pass C uses it)
//   WS (float2[H*N2])  @ 131072   : w^S
//   F  (float2[B*H*G*N2]) @ 262144 : chunk end states in s-space (s = z/ct),
//                                    overwritten in-place with init states by pass B
// total ~33.8 MB

__global__ void s4d_precompute(const float* __restrict__ log_dt,
                               const float* __restrict__ log_A_real,
                               const float* __restrict__ A_imag,
                               const float* __restrict__ C,
                               float2* __restrict__ W,
                               float2* __restrict__ CT,
                               float2* __restrict__ WS) {
    int t = blockIdx.x * blockDim.x + threadIdx.x;
    if (t >= Hk * N2k) return;
    int h = t >> 5;
    double dt  = exp((double)log_dt[h]);
    double are = -exp((double)log_A_real[t]);
    double aim = (double)A_imag[t];
    double dr = dt * are, di = dt * aim;
    double er  = exp(dr);
    double wre = er * cos(di), wim = er * sin(di);
    double denom = are * are + aim * aim;
    double tr = wre - 1.0, ti = wim;
    double qr = (tr * are + ti * aim) / denom;
    double qi = (ti * are - tr * aim) / denom;
    double c0 = (double)C[2 * t], c1 = (double)C[2 * t + 1];
    W[t]  = make_float2((float)wre, (float)wim);
    CT[t] = make_float2((float)(2.0 * (c0 * qr - c1 * qi)),
                        (float)(2.0 * (c0 * qi + c1 * qr)));
    double esr = exp((double)Sk * dr);
    double sdi = (double)Sk * di;
    WS[t] = make_float2((float)(esr * cos(sdi)), (float)(esr * sin(sdi)));
}

// Pass A: one thread per (b,h,c,half): local end-state (s-space) of 16 modes,
// zero init.  s <- w*s + u  (u real).
__global__ __launch_bounds__(256, 4) void s4d_passA(const float* __restrict__ u,
                                                    const float2* __restrict__ W,
                                                    float2* __restrict__ F) {
    int t = blockIdx.x * blockDim.x + threadIdx.x; // [0, B*H*G*2)
    int p = t & 1;                 // mode half
    int c = (t >> 1) & (Gk - 1);
    int rest = t >> 6;             // b*H + h
    int h = rest & (Hk - 1);

    float wx[HALF_MODES], wy[HALF_MODES], sr[HALF_MODES], si[HALF_MODES];
    int nbase = (h << 5) + p * HALF_MODES;
    #pragma unroll
    for (int nn = 0; nn < HALF_MODES; ++nn) {
        float2 w = W[nbase + nn];
        wx[nn] = w.x; wy[nn] = w.y;
        sr[nn] = 0.f; si[nn] = 0.f;
    }

    const float4* up = (const float4*)(u + (size_t)rest * Lk + (size_t)c * Sk);
    for (int j = 0; j < Sk / 4; ++j) {
        float4 uv = up[j];
        float us[4] = {uv.x, uv.y, uv.z, uv.w};
        #pragma unroll
        for (int k = 0; k < 4; ++k) {
            float uval = us[k];
            #pragma unroll
            for (int nn = 0; nn < HALF_MODES; ++nn) {
                float sr2 = fmaf(wx[nn], sr[nn], fmaf(-wy[nn], si[nn], uval));
                float si2 = fmaf(wx[nn], si[nn], wy[nn] * sr[nn]);
                sr[nn] = sr2; si[nn] = si2;
            }
        }
    }
    // F[(rest*G + c)*N2 + n], n = p*16 + nn ; write as 8 float4s (128B contig)
    float4* f4 = (float4*)(F + ((((rest << 5) + c) << 5) + p * HALF_MODES));
    #pragma unroll
    for (int i = 0; i < HALF_MODES / 2; ++i) {
        float4 v; v.x = sr[2 * i]; v.y = si[2 * i]; v.z = sr[2 * i + 1]; v.w = si[2 * i + 1];
        f4[i] = v;
    }
}

// Pass B: one thread per (b,h,n): exclusive scan over chunks with mult w^S.
// In-place on F (s-space).
__global__ __launch_bounds__(256) void s4d_passB(const float2* __restrict__ WS,
                                                 float2* __restrict__ F) {
    int t = blockIdx.x * blockDim.x + threadIdx.x; // [0, B*H*N2)
    int n = t & (N2k - 1);
    int rest = t >> 5;             // b*H + h
    int h = rest & (Hk - 1);
    float2 ws = WS[(h << 5) | n];
    float zr = 0.f, zi = 0.f;
    #pragma unroll
    for (int c = 0; c < Gk; ++c) {
        int idx = (((rest << 5) + c) << 5) | n;
        float2 f = F[idx];
        F[idx] = make_float2(zr, zi);
        float zr2 = fmaf(ws.x, zr, -ws.y * zi) + f.x;
        float zi2 = fmaf(ws.x, zi,  ws.y * zr) + f.y;
        zr = zr2; zi = zi2;
    }
}

// Pass C: one thread per (b,h,c,half): 16 modes in registers, seeded from I;
// pair lanes (t XOR 1) exchange per-element partial sums via shfl_xor;
// lanes alternate float4 stores by parity.
__global__ __launch_bounds__(256, 4) void s4d_passC(const float* __restrict__ u,
                                                    const float2* __restrict__ W,
                                                    const float2* __restrict__ CT,
                                                    const float2* __restrict__ F,
                                                    const float* __restrict__ Dv,
                                                    float* __restrict__ y) {
    int t = blockIdx.x * blockDim.x + threadIdx.x; // [0, B*H*G*2)
    int p = t & 1;
    int c = (t >> 1) & (Gk - 1);
    int rest = t >> 6;             // b*H + h
    int h = rest & (Hk - 1);

    float wx[HALF_MODES], wy[HALF_MODES], ctx[HALF_MODES], cty[HALF_MODES];
    float sr[HALF_MODES], si[HALF_MODES];
    int nbase = (h << 5) + p * HALF_MODES;
    const float4* f4 = (const float4*)(F + ((((rest << 5) + c) << 5) + p * HALF_MODES));
    #pragma unroll
    for (int nn = 0; nn < HALF_MODES; ++nn) {
        float2 w  = W[nbase + nn];
        float2 cc = CT[nbase + nn];
        wx[nn] = w.x;  wy[nn] = w.y;
        ctx[nn] = cc.x; cty[nn] = cc.y;
    }
    #pragma unroll
    for (int i = 0; i < HALF_MODES / 2; ++i) {
        float4 v = f4[i];
        sr[2 * i] = v.x; si[2 * i] = v.y; sr[2 * i + 1] = v.z; si[2 * i + 1] = v.w;
    }

    float Dh = Dv[h];
    size_t base = (size_t)rest * Lk + (size_t)c * Sk;
    const float4* up = (const float4*)(u + base);
    float4* yp = (float4*)(y + base);

    for (int j = 0; j < Sk / 4; ++j) {
        float4 uv = up[j];
        float us[4] = {uv.x, uv.y, uv.z, uv.w};
        float part[4];
        #pragma unroll
        for (int k = 0; k < 4; ++k) {
            float uval = us[k];
            float acc = 0.f;
            #pragma unroll
            for (int nn = 0; nn < HALF_MODES; ++nn) {
                float sr2 = fmaf(wx[nn], sr[nn], fmaf(-wy[nn], si[nn], uval));
                float si2 = fmaf(wx[nn], si[nn], wy[nn] * sr[nn]);
                sr[nn] = sr2; si[nn] = si2;
                acc = fmaf(ctx[nn], sr2, acc);
                acc = fmaf(-cty[nn], si2, acc);
            }
            part[k] = acc;
        }
        // combine halves (both lanes of the pair get the full sum)
        float4 yv;
        float tot0 = part[0] + __shfl_xor(part[0], 1);
        float tot1 = part[1] + __shfl_xor(part[1], 1);
        float tot2 = part[2] + __shfl_xor(part[2], 1);
        float tot3 = part[3] + __shfl_xor(part[3], 1);
        yv.x = fmaf(Dh, us[0], tot0);
        yv.y = fmaf(Dh, us[1], tot1);
        yv.z = fmaf(Dh, us[2], tot2);
        yv.w = fmaf(Dh, us[3], tot3);
        if (((j ^ p) & 1) == 0) yp[j] = yv;  // lanes alternate stores
    }
}

extern "C" void kernel_launch(void* const* d_in, const int* in_sizes, int n_in,
                              void* d_out, int out_size, void* d_ws, size_t ws_size,
                              hipStream_t stream) {
    const float* u           = (const float*)d_in[0];
    const float* log_dt      = (const float*)d_in[1];
    const float* log_A_real  = (const float*)d_in[2];
    const float* A_imag      = (const float*)d_in[3];
    const float* C           = (const float*)d_in[4];
    const float* D           = (const float*)d_in[5];
    float* y = (float*)d_out;

    char* ws = (char*)d_ws;
    float2* W  = (float2*)(ws);
    float2* CT = (float2*)(ws + 65536);
    float2* WS = (float2*)(ws + 131072);
    float2* F  = (float2*)(ws + 262144);

    s4d_precompute<<<(Hk * N2k) / 256, 256, 0, stream>>>(log_dt, log_A_real,
                                                         A_imag, C, W, CT, WS);
    s4d_passA<<<(Bk * Hk * Gk * 2) / 256, 256, 0, stream>>>(u, W, F);
    s4d_passB<<<(Bk * Hk * N2k) / 256, 256, 0, stream>>>(WS, F);
    s4d_passC<<<(Bk * Hk * Gk * 2) / 256, 256, 0, stream>>>(u, W, CT, F, D, y);
}

// Round 3
// 495.404 us; speedup vs baseline: 1.8459x; 1.8459x over previous
//
#include <hip/hip_runtime.h>

#define Bk 16
#define Hk 256
#define Lk 8192
#define N2k 32
#define Sk 256
#define Gk (Lk / Sk) // 32

// Workspace layout (bytes):
//   W  (float2[H*N2])  @ 0        : w = exp(dt*A)
//   CT (float2[H*N2])  @ 65536    : 2*C*(w-1)/A   (only pass C uses it)
//   WS (float2[H*N2])  @ 131072   : w^S
//   F  (float2[B*H*G*N2]) @ 262144 : chunk end states in s-space (s = z/ct),
//                                    overwritten in-place with init states by pass B
// total ~33.8 MB

__global__ void s4d_precompute(const float* __restrict__ log_dt,
                               const float* __restrict__ log_A_real,
                               const float* __restrict__ A_imag,
                               const float* __restrict__ C,
                               float2* __restrict__ W,
                               float2* __restrict__ CT,
                               float2* __restrict__ WS) {
    int t = blockIdx.x * blockDim.x + threadIdx.x;
    if (t >= Hk * N2k) return;
    int h = t >> 5;
    double dt  = exp((double)log_dt[h]);
    double are = -exp((double)log_A_real[t]);
    double aim = (double)A_imag[t];
    double dr = dt * are, di = dt * aim;
    double er  = exp(dr);
    double wre = er * cos(di), wim = er * sin(di);
    double denom = are * are + aim * aim;
    double tr = wre - 1.0, ti = wim;
    double qr = (tr * are + ti * aim) / denom;
    double qi = (ti * are - tr * aim) / denom;
    double c0 = (double)C[2 * t], c1 = (double)C[2 * t + 1];
    W[t]  = make_float2((float)wre, (float)wim);
    CT[t] = make_float2((float)(2.0 * (c0 * qr - c1 * qi)),
                        (float)(2.0 * (c0 * qi + c1 * qr)));
    double esr = exp((double)Sk * dr);
    double sdi = (double)Sk * di;
    WS[t] = make_float2((float)(esr * cos(sdi)), (float)(esr * sin(sdi)));
}

// Pass A: one thread per (b,h,c,quarter): 8 modes, s-space (s <- w*s + u),
// zero init. No CT needed. Small state (~32 floats) -> high occupancy.
// NOTE: no second __launch_bounds__ arg — (256,4) made the compiler cap VGPRs
// at 64 and spill to scratch (round-2 FETCH 2 GB). Default heuristic gives ~4
// waves/SIMD budget which is what we want.
__global__ __launch_bounds__(256) void s4d_passA(const float* __restrict__ u,
                                                 const float2* __restrict__ W,
                                                 float2* __restrict__ F) {
    int t = blockIdx.x * blockDim.x + threadIdx.x; // [0, B*H*G*4)
    int q = t & 3;                 // mode quarter (8 modes)
    int c = (t >> 2) & (Gk - 1);
    int rest = t >> 7;             // b*H + h
    int h = rest & (Hk - 1);

    float wx[8], wy[8], sr[8], si[8];
    int nbase = (h << 5) + q * 8;
    #pragma unroll
    for (int nn = 0; nn < 8; ++nn) {
        float2 w = W[nbase + nn];
        wx[nn] = w.x; wy[nn] = w.y;
        sr[nn] = 0.f; si[nn] = 0.f;
    }

    const float4* up = (const float4*)(u + (size_t)rest * Lk + (size_t)c * Sk);
    for (int j = 0; j < Sk / 4; ++j) {
        float4 uv = up[j];
        float us[4] = {uv.x, uv.y, uv.z, uv.w};
        #pragma unroll
        for (int k = 0; k < 4; ++k) {
            float uval = us[k];
            #pragma unroll
            for (int nn = 0; nn < 8; ++nn) {
                float sr2 = fmaf(wx[nn], sr[nn], fmaf(-wy[nn], si[nn], uval));
                float si2 = fmaf(wx[nn], si[nn], wy[nn] * sr[nn]);
                sr[nn] = sr2; si[nn] = si2;
            }
        }
    }
    // F[(rest*G + c)*N2 + n], n = q*8 + nn ; 4 float4s (64B contig per thread)
    float4* f4 = (float4*)(F + ((((rest << 5) + c) << 5) + q * 8));
    #pragma unroll
    for (int i = 0; i < 4; ++i) {
        float4 v; v.x = sr[2 * i]; v.y = si[2 * i]; v.z = sr[2 * i + 1]; v.w = si[2 * i + 1];
        f4[i] = v;
    }
}

// Pass B: one thread per (b,h,n): exclusive scan over chunks with mult w^S.
// In-place on F (s-space).
__global__ __launch_bounds__(256) void s4d_passB(const float2* __restrict__ WS,
                                                 float2* __restrict__ F) {
    int t = blockIdx.x * blockDim.x + threadIdx.x; // [0, B*H*N2)
    int n = t & (N2k - 1);
    int rest = t >> 5;             // b*H + h
    int h = rest & (Hk - 1);
    float2 ws = WS[(h << 5) | n];
    float zr = 0.f, zi = 0.f;
    #pragma unroll
    for (int c = 0; c < Gk; ++c) {
        int idx = (((rest << 5) + c) << 5) | n;
        float2 f = F[idx];
        F[idx] = make_float2(zr, zi);
        float zr2 = fmaf(ws.x, zr, -ws.y * zi) + f.x;
        float zi2 = fmaf(ws.x, zi,  ws.y * zr) + f.y;
        zr = zr2; zi = zi2;
    }
}

// Pass C: one thread per (b,h,c,half): 16 modes in registers (~96 state
// floats, fits default ~124-VGPR allocation with no spill), seeded from I;
// pair lanes (t XOR 1) exchange per-element partial sums via shfl_xor;
// lanes alternate float4 stores by parity.
__global__ __launch_bounds__(256) void s4d_passC(const float* __restrict__ u,
                                                 const float2* __restrict__ W,
                                                 const float2* __restrict__ CT,
                                                 const float2* __restrict__ F,
                                                 const float* __restrict__ Dv,
                                                 float* __restrict__ y) {
    int t = blockIdx.x * blockDim.x + threadIdx.x; // [0, B*H*G*2)
    int p = t & 1;
    int c = (t >> 1) & (Gk - 1);
    int rest = t >> 6;             // b*H + h
    int h = rest & (Hk - 1);

    float wx[16], wy[16], ctx[16], cty[16], sr[16], si[16];
    int nbase = (h << 5) + p * 16;
    const float4* f4 = (const float4*)(F + ((((rest << 5) + c) << 5) + p * 16));
    #pragma unroll
    for (int nn = 0; nn < 16; ++nn) {
        float2 w  = W[nbase + nn];
        float2 cc = CT[nbase + nn];
        wx[nn] = w.x;  wy[nn] = w.y;
        ctx[nn] = cc.x; cty[nn] = cc.y;
    }
    #pragma unroll
    for (int i = 0; i < 8; ++i) {
        float4 v = f4[i];
        sr[2 * i] = v.x; si[2 * i] = v.y; sr[2 * i + 1] = v.z; si[2 * i + 1] = v.w;
    }

    float Dh = Dv[h];
    size_t base = (size_t)rest * Lk + (size_t)c * Sk;
    const float4* up = (const float4*)(u + base);
    float4* yp = (float4*)(y + base);

    for (int j = 0; j < Sk / 4; ++j) {
        float4 uv = up[j];
        float us[4] = {uv.x, uv.y, uv.z, uv.w};
        float part[4];
        #pragma unroll
        for (int k = 0; k < 4; ++k) {
            float uval = us[k];
            float acc = 0.f;
            #pragma unroll
            for (int nn = 0; nn < 16; ++nn) {
                float sr2 = fmaf(wx[nn], sr[nn], fmaf(-wy[nn], si[nn], uval));
                float si2 = fmaf(wx[nn], si[nn], wy[nn] * sr[nn]);
                sr[nn] = sr2; si[nn] = si2;
                acc = fmaf(ctx[nn], sr2, acc);
                acc = fmaf(-cty[nn], si2, acc);
            }
            part[k] = acc;
        }
        // combine halves (both lanes of the pair get the full sum)
        float4 yv;
        float tot0 = part[0] + __shfl_xor(part[0], 1);
        float tot1 = part[1] + __shfl_xor(part[1], 1);
        float tot2 = part[2] + __shfl_xor(part[2], 1);
        float tot3 = part[3] + __shfl_xor(part[3], 1);
        yv.x = fmaf(Dh, us[0], tot0);
        yv.y = fmaf(Dh, us[1], tot1);
        yv.z = fmaf(Dh, us[2], tot2);
        yv.w = fmaf(Dh, us[3], tot3);
        if (((j ^ p) & 1) == 0) yp[j] = yv;  // lanes alternate stores
    }
}

extern "C" void kernel_launch(void* const* d_in, const int* in_sizes, int n_in,
                              void* d_out, int out_size, void* d_ws, size_t ws_size,
                              hipStream_t stream) {
    const float* u           = (const float*)d_in[0];
    const float* log_dt      = (const float*)d_in[1];
    const float* log_A_real  = (const float*)d_in[2];
    const float* A_imag      = (const float*)d_in[3];
    const float* C           = (const float*)d_in[4];
    const float* D           = (const float*)d_in[5];
    float* y = (float*)d_out;

    char* ws = (char*)d_ws;
    float2* W  = (float2*)(ws);
    float2* CT = (float2*)(ws + 65536);
    float2* WS = (float2*)(ws + 131072);
    float2* F  = (float2*)(ws + 262144);

    s4d_precompute<<<(Hk * N2k) / 256, 256, 0, stream>>>(log_dt, log_A_real,
                                                         A_imag, C, W, CT, WS);
    s4d_passA<<<(Bk * Hk * Gk * 4) / 256, 256, 0, stream>>>(u, W, F);
    s4d_passB<<<(Bk * Hk * N2k) / 256, 256, 0, stream>>>(WS, F);
    s4d_passC<<<(Bk * Hk * Gk * 2) / 256, 256, 0, stream>>>(u, W, CT, F, D, y);
}